// Round 19
// baseline (46.391 us; speedup 1.0000x reference)
//
#include <hip/hip_runtime.h>
#include <math.h>

#define HW 65536
#define NC 26
#define NB 2

// ws layout (bytes)
// cnt u32[320]: [208..259] P cursors/totals per pair, [260..311] T cursors/totals
#define PL_OFF    0          // u8 [2][65536]
#define TL_OFF    131072     // u8 [2][65536]
#define CNT_OFF   262144     // u32[320]
#define RES_OFF   263424     // f32 res[52][2]
#define BMP_OFF   264192     // u32 [2][52][256][8] = 851968 B
#define LISTP_OFF 1116160    // u16[52][65536] = 6815744 B
#define LISTT_OFF 7931904    // u16[52][65536]
#define MINP_OFF  14747648   // f32[52][65536] = 13631488 B
#define MINT_OFF  28379136   // f32[52][65536] (ends 42010624)

__global__ void k_labels(const float4* __restrict__ pred, const float4* __restrict__ targ,
                         uchar4* __restrict__ pl, uchar4* __restrict__ tl,
                         unsigned int* __restrict__ cnt) {
    int tid = threadIdx.x;
    if (blockIdx.x == 0) {
        for (int i = tid; i < 320; i += 128) cnt[i] = 0;
    }
    int idx = blockIdx.x * 128 + tid;   // 0..32767
    if (idx >= (NB * HW / 4)) return;
    int b = idx >> 14, q = idx & 16383;
    const float4* p = pred + ((size_t)b * NC << 14) + q;
    const float4* t = targ + ((size_t)b * NC << 14) + q;
    float4 bp = p[0]; uchar4 ap = {0, 0, 0, 0};
    float4 bt = t[0]; uchar4 at = {0, 0, 0, 0};
#pragma unroll
    for (int c = 1; c < NC; ++c) {
        float4 vp = p[(size_t)c << 14];
        if (vp.x > bp.x) { bp.x = vp.x; ap.x = (unsigned char)c; }
        if (vp.y > bp.y) { bp.y = vp.y; ap.y = (unsigned char)c; }
        if (vp.z > bp.z) { bp.z = vp.z; ap.z = (unsigned char)c; }
        if (vp.w > bp.w) { bp.w = vp.w; ap.w = (unsigned char)c; }
        float4 vt = t[(size_t)c << 14];
        if (vt.x > bt.x) { bt.x = vt.x; at.x = (unsigned char)c; }
        if (vt.y > bt.y) { bt.y = vt.y; at.y = (unsigned char)c; }
        if (vt.z > bt.z) { bt.z = vt.z; at.z = (unsigned char)c; }
        if (vt.w > bt.w) { bt.w = vt.w; at.w = (unsigned char)c; }
    }
    pl[idx] = ap;
    tl[idx] = at;
}

__device__ __forceinline__ bool is_boundary(const unsigned char* __restrict__ L, int hw, int c) {
    int y = hw >> 8, x = hw & 255;
    if (y == 0 || y == 255 || x == 0 || x == 255) return true;
    return (int)L[hw - 256] != c || (int)L[hw + 256] != c ||
           (int)L[hw - 1]   != c || (int)L[hw + 1]   != c;
}

// grid 512 = (b<<8)|y, block 256. Builds bitmaps AND compacts coordinate lists
// into fixed per-(pair) regions via block-level cursor reservation.
__global__ void k_rowbm(const unsigned char* __restrict__ pl,
                        const unsigned char* __restrict__ tl,
                        unsigned int* __restrict__ bmp,
                        unsigned int* __restrict__ cnt,
                        unsigned short* __restrict__ listP,
                        unsigned short* __restrict__ listT) {
    __shared__ unsigned bm[52][8];
    __shared__ unsigned lh[52];
    __shared__ unsigned lb[52];
    int tid = threadIdx.x;
    int b = blockIdx.x >> 8, y = blockIdx.x & 255;
    for (int i = tid; i < 416; i += 256) ((unsigned*)bm)[i] = 0;
    if (tid < 52) lh[tid] = 0;
    __syncthreads();
    const unsigned char* Lp = pl + (b << 16);
    const unsigned char* Lt = tl + (b << 16);
    int hw = (y << 8) | tid;
    int cp = Lp[hw];
    int ct = Lt[hw];
    bool bnp = is_boundary(Lp, hw, cp);
    bool bnt = is_boundary(Lt, hw, ct);
    unsigned rp = 0, rt = 0;
    if (bnp) {
        atomicOr(&bm[cp][tid >> 5], 1u << (tid & 31));
        rp = atomicAdd(&lh[cp], 1u);
    }
    if (bnt) {
        atomicOr(&bm[26 + ct][tid >> 5], 1u << (tid & 31));
        rt = atomicAdd(&lh[26 + ct], 1u);
    }
    __syncthreads();
    for (int i = tid; i < 416; i += 256) {
        int idx = i >> 3, w = i & 7;
        int m = idx < 26 ? 0 : 1;
        int c = idx < 26 ? idx : idx - 26;
        bmp[(((m * 52 + b * 26 + c) << 8) | y) * 8 + w] = bm[idx][w];
    }
    if (tid < 26)
        lb[tid] = lh[tid] ? atomicAdd(&cnt[208 + b * 26 + tid], lh[tid]) : 0u;
    else if (tid < 52)
        lb[tid] = lh[tid] ? atomicAdd(&cnt[260 + b * 26 + (tid - 26)], lh[tid]) : 0u;
    __syncthreads();
    if (bnp) listP[((unsigned)(b * 26 + cp) << 16) + lb[cp] + rp] = (unsigned short)hw;
    if (bnt) listT[((unsigned)(b * 26 + ct) << 16) + lb[26 + ct] + rt] = (unsigned short)hw;
}

// Branchless nearest set bit in row r; word 8 of the stride-9 row = occupancy mask.
__device__ __forceinline__ int row_dx(const unsigned* sb, int r, int xw, int xb) {
    const unsigned* row = sb + r * 9;
    unsigned RM = row[8];
    if (!RM) return 999;
    int dxmin = 999;
    unsigned m = row[xw];
    unsigned le = 0xFFFFFFFFu >> (31 - xb);    // bits 0..xb
    unsigned lm = m & le;
    if (lm) dxmin = xb - 31 + __clz(lm);
    unsigned rmm = m & ~le;
    if (rmm) dxmin = min(dxmin, (__ffs(rmm) - 1) - xb);
    unsigned Lm = RM & ((1u << xw) - 1u);      // nonzero words strictly left
    if (Lm) {
        int w1 = 31 - __clz(Lm);
        unsigned m1 = row[w1];
        dxmin = min(dxmin, xb + ((xw - w1) << 5) - (31 - __clz(m1)));
    }
    unsigned Rm = RM >> (xw + 1);              // nonzero words strictly right
    if (Rm) {
        int w2 = xw + __ffs(Rm);
        unsigned m2 = row[w2];
        dxmin = min(dxmin, ((w2 - xw) << 5) + (__ffs(m2) - 1) - xb);
    }
    return dxmin;
}

// grid (12, 52, 2), block 256: ring-PAIR (k, k+1) per iteration -> 4 independent
// row_dx chains issued together (2x ILP on the LDS latency chain), exit check
// every 2 rings (conservative; extra candidates are true distances, min exact).
__global__ __launch_bounds__(256) void k_ring(
        const unsigned int* __restrict__ cnt,
        const unsigned int* __restrict__ bmp,
        const unsigned short* __restrict__ listP,
        const unsigned short* __restrict__ listT,
        float* __restrict__ minP, float* __restrict__ minT) {
    int pair = blockIdx.y;
    int dir = blockIdx.z;
    unsigned ns = cnt[(dir ? 260 : 208) + pair];
    unsigned i0 = blockIdx.x * 256u;
    if (i0 >= ns) return;
    unsigned nt = cnt[(dir ? 208 : 260) + pair];
    if (nt == 0) return;   // k_select emits sqrt(1e10); min-values never read
    const unsigned short* src = (dir ? listT : listP) + ((unsigned)pair << 16);
    float* outv = (dir ? minT : minP) + ((unsigned)pair << 16);

    __shared__ unsigned sb[256 * 9];
    int tid = threadIdx.x;
    {   // stage target bitmap (dir0 tgt=T(m1), dir1 tgt=P(m0)) into padded layout
        const uint4* g4 = (const uint4*)(bmp + ((unsigned)((dir ? 0 : 52) + pair) << 11));
#pragma unroll
        for (int t = 0; t < 2; ++t) {
            int idx = tid + t * 256;          // 0..511 (uint4 index)
            uint4 v = g4[idx];
            unsigned* row = sb + (idx >> 1) * 9 + ((idx & 1) << 2);
            row[0] = v.x; row[1] = v.y; row[2] = v.z; row[3] = v.w;
        }
    }
    __syncthreads();
    {   // per-row word-occupancy mask -> word 8
        const unsigned* row = sb + tid * 9;
        unsigned rm = 0;
#pragma unroll
        for (int w = 0; w < 8; ++w) rm |= (row[w] ? 1u : 0u) << w;
        sb[tid * 9 + 8] = rm;
    }
    __syncthreads();

    unsigned stride = gridDim.x * 256u;
    for (unsigned ib = i0; ib < ns; ib += stride) {
        unsigned i = ib + tid;
        if (i >= ns) continue;
        unsigned h = src[i];
        int x = (int)(h & 255u);
        int sy = (int)(h >> 8);
        int xw = x >> 5, xb = x & 31;
        int best = 0x40000000;
        for (int k = 0; k < 256; k += 2) {
            int k2a = k * k;
            if (k2a >= best) break;
            int raA = sy - k, rbA = sy + k;
            if (raA < 0 && rbA > 255) break;
            int k2b = (k + 1) * (k + 1);
            int raB = raA - 1, rbB = rbA + 1;
            int c0 = 0x40000000, c1 = 0x40000000, c2 = 0x40000000, c3 = 0x40000000;
            if (raA >= 0) {
                int dx = row_dx(sb, raA, xw, xb);
                if (dx < 999) c0 = k2a + dx * dx;
            }
            if (k && rbA < 256) {
                int dx = row_dx(sb, rbA, xw, xb);
                if (dx < 999) c1 = k2a + dx * dx;
            }
            if (raB >= 0) {
                int dx = row_dx(sb, raB, xw, xb);
                if (dx < 999) c2 = k2b + dx * dx;
            }
            if (rbB < 256) {
                int dx = row_dx(sb, rbB, xw, xb);
                if (dx < 999) c3 = k2b + dx * dx;
            }
            best = min(best, min(min(c0, c1), min(c2, c3)));
        }
        outv[i] = (float)best;
    }
}

// grid: (pair=52, dir=2), block 256. 4-way sub-histograms cut same-address LDS
// atomic serialization (d^2 values cluster into a few coarse bins).
__global__ void k_select(const unsigned int* __restrict__ cnt,
                         const float* __restrict__ minP, const float* __restrict__ minT,
                         float* __restrict__ res) {
    int pair = blockIdx.x;
    int dir = blockIdx.y;
    unsigned ns = cnt[(dir ? 260 : 208) + pair];
    unsigned nt = cnt[(dir ? 208 : 260) + pair];
    const float* vals = (dir ? minT : minP) + ((unsigned)pair << 16);
    int tid = threadIdx.x;

    if (ns == 0) { if (tid == 0) res[pair * 2 + dir] = nanf(""); return; }
    if (nt == 0) { if (tid == 0) res[pair * 2 + dir] = sqrtf(1e10f); return; }

    __shared__ unsigned hist4[4][1024];
    __shared__ unsigned f1[4][128], f2[4][128];
    __shared__ int s_binlo, s_binhi, s_below_lo, s_below_hi;

    for (int i = tid; i < 4096; i += 256) ((unsigned*)hist4)[i] = 0;
    __syncthreads();
    int sub = tid & 3;
    for (unsigned i = tid; i < ns; i += 256) {
        int v = (int)vals[i];
        atomicAdd(&hist4[sub][v >> 7], 1u);
    }
    __syncthreads();

    float idxf = 0.95f * ((float)ns - 1.0f);
    if (idxf < 0.f) idxf = 0.f;
    int klo = (int)floorf(idxf);
    int khi = (int)ceilf(idxf);

    if (tid == 0) {
        unsigned cum = 0;
        int binlo = -1, binhi = -1, below_lo = 0, below_hi = 0;
        for (int bkt = 0; bkt < 1024; ++bkt) {
            unsigned h = hist4[0][bkt] + hist4[1][bkt] + hist4[2][bkt] + hist4[3][bkt];
            if (binlo < 0 && cum + h > (unsigned)klo) { binlo = bkt; below_lo = (int)cum; }
            if (binhi < 0 && cum + h > (unsigned)khi) { binhi = bkt; below_hi = (int)cum; }
            cum += h;
            if (binhi >= 0) break;
        }
        s_binlo = binlo; s_binhi = binhi; s_below_lo = below_lo; s_below_hi = below_hi;
    }
    __syncthreads();
    for (int i = tid; i < 1024; i += 256) { ((unsigned*)f1)[i] = 0; ((unsigned*)f2)[i] = 0; }
    __syncthreads();
    int binlo = s_binlo, binhi = s_binhi;
    for (unsigned i = tid; i < ns; i += 256) {
        int v = (int)vals[i];
        int bkt = v >> 7;
        if (bkt == binlo) atomicAdd(&f1[sub][v & 127], 1u);
        if (bkt == binhi && binhi != binlo) atomicAdd(&f2[sub][v & 127], 1u);
    }
    __syncthreads();
    if (tid == 0) {
        int rlo = klo - s_below_lo;
        unsigned cum = 0; int d2lo = binlo << 7, d2hi = binhi << 7;
        for (int j = 0; j < 128; ++j) {
            cum += f1[0][j] + f1[1][j] + f1[2][j] + f1[3][j];
            if ((int)cum > rlo) { d2lo = (binlo << 7) + j; break; }
        }
        if (binhi == binlo) {
            int rhi = khi - s_below_lo;
            cum = 0;
            for (int j = 0; j < 128; ++j) {
                cum += f1[0][j] + f1[1][j] + f1[2][j] + f1[3][j];
                if ((int)cum > rhi) { d2hi = (binlo << 7) + j; break; }
            }
        } else {
            int rhi = khi - s_below_hi;
            cum = 0;
            for (int j = 0; j < 128; ++j) {
                cum += f2[0][j] + f2[1][j] + f2[2][j] + f2[3][j];
                if ((int)cum > rhi) { d2hi = (binhi << 7) + j; break; }
            }
        }
        float vlo = sqrtf((float)d2lo);
        float vhi = sqrtf((float)d2hi);
        float frac = idxf - floorf(idxf);
        res[pair * 2 + dir] = vlo + (vhi - vlo) * frac;
    }
}

// 1 block, 128 threads: parallel-load res+presence into LDS, lane 0 combines.
__global__ void k_final(const unsigned int* __restrict__ cnt, const float* __restrict__ res,
                        float* __restrict__ out) {
    __shared__ float s_res[104];
    __shared__ unsigned s_pres[52];
    int tid = threadIdx.x;
    if (tid < 104) s_res[tid] = res[tid];
    if (tid < 52) s_pres[tid] = cnt[260 + tid];
    __syncthreads();
    if (tid != 0) return;
    float total = 0.f, nvalid = 0.f;
    bool anyv = false;
    for (int b = 0; b < NB; ++b) {
        float num = 0.f, den = 0.f;
        for (int c = 0; c < NC; ++c) {
            int pair = b * NC + c;
            bool present = s_pres[pair] > 0;
            float dpt = s_res[pair * 2];
            float dtp = s_res[pair * 2 + 1];
            float hd;
            if (isnan(dpt) || isnan(dtp)) hd = nanf("");
            else hd = fmaxf(dpt, dtp);
            if (present) { num += hd; den += 1.f; }
        }
        float bm = num / fmaxf(den, 1.f);
        if (den > 0.f) { total += bm; nvalid += 1.f; anyv = true; }
    }
    out[0] = anyv ? (total / fmaxf(nvalid, 1.f)) : INFINITY;
}

extern "C" void kernel_launch(void* const* d_in, const int* in_sizes, int n_in,
                              void* d_out, int out_size, void* d_ws, size_t ws_size,
                              hipStream_t stream) {
    const float* pred = (const float*)d_in[0];
    const float* targ = (const float*)d_in[1];
    float* out = (float*)d_out;
    char* ws = (char*)d_ws;

    unsigned char* pl = (unsigned char*)(ws + PL_OFF);
    unsigned char* tl = (unsigned char*)(ws + TL_OFF);
    unsigned int* cnt = (unsigned int*)(ws + CNT_OFF);
    float* res = (float*)(ws + RES_OFF);
    unsigned int* bmp = (unsigned int*)(ws + BMP_OFF);
    unsigned short* listP = (unsigned short*)(ws + LISTP_OFF);
    unsigned short* listT = (unsigned short*)(ws + LISTT_OFF);
    float* minP = (float*)(ws + MINP_OFF);
    float* minT = (float*)(ws + MINT_OFF);

    k_labels<<<256, 128, 0, stream>>>((const float4*)pred, (const float4*)targ,
                                      (uchar4*)pl, (uchar4*)tl, cnt);
    k_rowbm<<<512, 256, 0, stream>>>(pl, tl, bmp, cnt, listP, listT);
    k_ring<<<dim3(12, 52, 2), 256, 0, stream>>>(cnt, bmp, listP, listT, minP, minT);
    k_select<<<dim3(52, 2), 256, 0, stream>>>(cnt, minP, minT, res);
    k_final<<<1, 128, 0, stream>>>(cnt, res, out);
}

// Round 20
// 45.248 us; speedup vs baseline: 1.0253x; 1.0253x over previous
//
#include <hip/hip_runtime.h>
#include <math.h>

#define HW 65536
#define NC 26
#define NB 2

// ws layout (bytes)
// cnt u32[320]: [208..259] P cursors/totals per pair, [260..311] T cursors/totals
#define PL_OFF    0          // u8 [2][65536]
#define TL_OFF    131072     // u8 [2][65536]
#define CNT_OFF   262144     // u32[320]
#define RES_OFF   263424     // f32 res[52][2]
#define BMP_OFF   264192     // u32 [2][52][256][8] = 851968 B
#define LISTP_OFF 1116160    // u16[52][65536] = 6815744 B
#define LISTT_OFF 7931904    // u16[52][65536]
#define MINP_OFF  14747648   // f32[52][65536] = 13631488 B
#define MINT_OFF  28379136   // f32[52][65536] (ends 42010624)

__global__ void k_labels(const float4* __restrict__ pred, const float4* __restrict__ targ,
                         uchar4* __restrict__ pl, uchar4* __restrict__ tl,
                         unsigned int* __restrict__ cnt) {
    int tid = threadIdx.x;
    if (blockIdx.x == 0) {
        for (int i = tid; i < 320; i += 128) cnt[i] = 0;
    }
    int idx = blockIdx.x * 128 + tid;   // 0..32767
    if (idx >= (NB * HW / 4)) return;
    int b = idx >> 14, q = idx & 16383;
    const float4* p = pred + ((size_t)b * NC << 14) + q;
    const float4* t = targ + ((size_t)b * NC << 14) + q;
    float4 bp = p[0]; uchar4 ap = {0, 0, 0, 0};
    float4 bt = t[0]; uchar4 at = {0, 0, 0, 0};
#pragma unroll
    for (int c = 1; c < NC; ++c) {
        float4 vp = p[(size_t)c << 14];
        if (vp.x > bp.x) { bp.x = vp.x; ap.x = (unsigned char)c; }
        if (vp.y > bp.y) { bp.y = vp.y; ap.y = (unsigned char)c; }
        if (vp.z > bp.z) { bp.z = vp.z; ap.z = (unsigned char)c; }
        if (vp.w > bp.w) { bp.w = vp.w; ap.w = (unsigned char)c; }
        float4 vt = t[(size_t)c << 14];
        if (vt.x > bt.x) { bt.x = vt.x; at.x = (unsigned char)c; }
        if (vt.y > bt.y) { bt.y = vt.y; at.y = (unsigned char)c; }
        if (vt.z > bt.z) { bt.z = vt.z; at.z = (unsigned char)c; }
        if (vt.w > bt.w) { bt.w = vt.w; at.w = (unsigned char)c; }
    }
    pl[idx] = ap;
    tl[idx] = at;
}

__device__ __forceinline__ bool is_boundary(const unsigned char* __restrict__ L, int hw, int c) {
    int y = hw >> 8, x = hw & 255;
    if (y == 0 || y == 255 || x == 0 || x == 255) return true;
    return (int)L[hw - 256] != c || (int)L[hw + 256] != c ||
           (int)L[hw - 1]   != c || (int)L[hw + 1]   != c;
}

// grid 512 = (b<<8)|y, block 256. Builds bitmaps AND compacts coordinate lists
// into fixed per-(pair) regions via block-level cursor reservation.
__global__ void k_rowbm(const unsigned char* __restrict__ pl,
                        const unsigned char* __restrict__ tl,
                        unsigned int* __restrict__ bmp,
                        unsigned int* __restrict__ cnt,
                        unsigned short* __restrict__ listP,
                        unsigned short* __restrict__ listT) {
    __shared__ unsigned bm[52][8];
    __shared__ unsigned lh[52];
    __shared__ unsigned lb[52];
    int tid = threadIdx.x;
    int b = blockIdx.x >> 8, y = blockIdx.x & 255;
    for (int i = tid; i < 416; i += 256) ((unsigned*)bm)[i] = 0;
    if (tid < 52) lh[tid] = 0;
    __syncthreads();
    const unsigned char* Lp = pl + (b << 16);
    const unsigned char* Lt = tl + (b << 16);
    int hw = (y << 8) | tid;
    int cp = Lp[hw];
    int ct = Lt[hw];
    bool bnp = is_boundary(Lp, hw, cp);
    bool bnt = is_boundary(Lt, hw, ct);
    unsigned rp = 0, rt = 0;
    if (bnp) {
        atomicOr(&bm[cp][tid >> 5], 1u << (tid & 31));
        rp = atomicAdd(&lh[cp], 1u);
    }
    if (bnt) {
        atomicOr(&bm[26 + ct][tid >> 5], 1u << (tid & 31));
        rt = atomicAdd(&lh[26 + ct], 1u);
    }
    __syncthreads();
    for (int i = tid; i < 416; i += 256) {
        int idx = i >> 3, w = i & 7;
        int m = idx < 26 ? 0 : 1;
        int c = idx < 26 ? idx : idx - 26;
        bmp[(((m * 52 + b * 26 + c) << 8) | y) * 8 + w] = bm[idx][w];
    }
    if (tid < 26)
        lb[tid] = lh[tid] ? atomicAdd(&cnt[208 + b * 26 + tid], lh[tid]) : 0u;
    else if (tid < 52)
        lb[tid] = lh[tid] ? atomicAdd(&cnt[260 + b * 26 + (tid - 26)], lh[tid]) : 0u;
    __syncthreads();
    if (bnp) listP[((unsigned)(b * 26 + cp) << 16) + lb[cp] + rp] = (unsigned short)hw;
    if (bnt) listT[((unsigned)(b * 26 + ct) << 16) + lb[26 + ct] + rt] = (unsigned short)hw;
}

// Branchless nearest set bit in row r; word 8 of the stride-9 row = occupancy mask.
__device__ __forceinline__ int row_dx(const unsigned* sb, int r, int xw, int xb) {
    const unsigned* row = sb + r * 9;
    unsigned RM = row[8];
    if (!RM) return 999;
    int dxmin = 999;
    unsigned m = row[xw];
    unsigned le = 0xFFFFFFFFu >> (31 - xb);    // bits 0..xb
    unsigned lm = m & le;
    if (lm) dxmin = xb - 31 + __clz(lm);
    unsigned rmm = m & ~le;
    if (rmm) dxmin = min(dxmin, (__ffs(rmm) - 1) - xb);
    unsigned Lm = RM & ((1u << xw) - 1u);      // nonzero words strictly left
    if (Lm) {
        int w1 = 31 - __clz(Lm);
        unsigned m1 = row[w1];
        dxmin = min(dxmin, xb + ((xw - w1) << 5) - (31 - __clz(m1)));
    }
    unsigned Rm = RM >> (xw + 1);              // nonzero words strictly right
    if (Rm) {
        int w2 = xw + __ffs(Rm);
        unsigned m2 = row[w2];
        dxmin = min(dxmin, ((w2 - xw) << 5) + (__ffs(m2) - 1) - xb);
    }
    return dxmin;
}

// grid (12, 52, 2), block 256: ring-PAIR (k, k+1) per iteration -> 4 independent
// row_dx chains issued together (2x ILP on the LDS latency chain), exit check
// every 2 rings (conservative; extra candidates are true distances, min exact).
__global__ __launch_bounds__(256) void k_ring(
        const unsigned int* __restrict__ cnt,
        const unsigned int* __restrict__ bmp,
        const unsigned short* __restrict__ listP,
        const unsigned short* __restrict__ listT,
        float* __restrict__ minP, float* __restrict__ minT) {
    int pair = blockIdx.y;
    int dir = blockIdx.z;
    unsigned ns = cnt[(dir ? 260 : 208) + pair];
    unsigned i0 = blockIdx.x * 256u;
    if (i0 >= ns) return;
    unsigned nt = cnt[(dir ? 208 : 260) + pair];
    if (nt == 0) return;   // k_select emits sqrt(1e10); min-values never read
    const unsigned short* src = (dir ? listT : listP) + ((unsigned)pair << 16);
    float* outv = (dir ? minT : minP) + ((unsigned)pair << 16);

    __shared__ unsigned sb[256 * 9];
    int tid = threadIdx.x;
    {   // stage target bitmap (dir0 tgt=T(m1), dir1 tgt=P(m0)) into padded layout
        const uint4* g4 = (const uint4*)(bmp + ((unsigned)((dir ? 0 : 52) + pair) << 11));
#pragma unroll
        for (int t = 0; t < 2; ++t) {
            int idx = tid + t * 256;          // 0..511 (uint4 index)
            uint4 v = g4[idx];
            unsigned* row = sb + (idx >> 1) * 9 + ((idx & 1) << 2);
            row[0] = v.x; row[1] = v.y; row[2] = v.z; row[3] = v.w;
        }
    }
    __syncthreads();
    {   // per-row word-occupancy mask -> word 8
        const unsigned* row = sb + tid * 9;
        unsigned rm = 0;
#pragma unroll
        for (int w = 0; w < 8; ++w) rm |= (row[w] ? 1u : 0u) << w;
        sb[tid * 9 + 8] = rm;
    }
    __syncthreads();

    unsigned stride = gridDim.x * 256u;
    for (unsigned ib = i0; ib < ns; ib += stride) {
        unsigned i = ib + tid;
        if (i >= ns) continue;
        unsigned h = src[i];
        int x = (int)(h & 255u);
        int sy = (int)(h >> 8);
        int xw = x >> 5, xb = x & 31;
        int best = 0x40000000;
        for (int k = 0; k < 256; k += 2) {
            int k2a = k * k;
            if (k2a >= best) break;
            int raA = sy - k, rbA = sy + k;
            if (raA < 0 && rbA > 255) break;
            int k2b = (k + 1) * (k + 1);
            int raB = raA - 1, rbB = rbA + 1;
            int c0 = 0x40000000, c1 = 0x40000000, c2 = 0x40000000, c3 = 0x40000000;
            if (raA >= 0) {
                int dx = row_dx(sb, raA, xw, xb);
                if (dx < 999) c0 = k2a + dx * dx;
            }
            if (k && rbA < 256) {
                int dx = row_dx(sb, rbA, xw, xb);
                if (dx < 999) c1 = k2a + dx * dx;
            }
            if (raB >= 0) {
                int dx = row_dx(sb, raB, xw, xb);
                if (dx < 999) c2 = k2b + dx * dx;
            }
            if (rbB < 256) {
                int dx = row_dx(sb, rbB, xw, xb);
                if (dx < 999) c3 = k2b + dx * dx;
            }
            best = min(best, min(min(c0, c1), min(c2, c3)));
        }
        outv[i] = (float)best;
    }
}

// grid: (pair=52, dir=2), block 256
__global__ void k_select(const unsigned int* __restrict__ cnt,
                         const float* __restrict__ minP, const float* __restrict__ minT,
                         float* __restrict__ res) {
    int pair = blockIdx.x;
    int dir = blockIdx.y;
    unsigned ns = cnt[(dir ? 260 : 208) + pair];
    unsigned nt = cnt[(dir ? 208 : 260) + pair];
    const float* vals = (dir ? minT : minP) + ((unsigned)pair << 16);
    int tid = threadIdx.x;

    if (ns == 0) { if (tid == 0) res[pair * 2 + dir] = nanf(""); return; }
    if (nt == 0) { if (tid == 0) res[pair * 2 + dir] = sqrtf(1e10f); return; }

    __shared__ unsigned hist[1024];
    __shared__ unsigned f1[128], f2[128];
    __shared__ int s_binlo, s_binhi, s_below_lo, s_below_hi;

    for (int i = tid; i < 1024; i += 256) hist[i] = 0;
    __syncthreads();
    for (unsigned i = tid; i < ns; i += 256) {
        int v = (int)vals[i];
        atomicAdd(&hist[v >> 7], 1u);
    }
    __syncthreads();

    float idxf = 0.95f * ((float)ns - 1.0f);
    if (idxf < 0.f) idxf = 0.f;
    int klo = (int)floorf(idxf);
    int khi = (int)ceilf(idxf);

    if (tid == 0) {
        unsigned cum = 0;
        int binlo = -1, binhi = -1, below_lo = 0, below_hi = 0;
        for (int bkt = 0; bkt < 1024; ++bkt) {
            unsigned h = hist[bkt];
            if (binlo < 0 && cum + h > (unsigned)klo) { binlo = bkt; below_lo = (int)cum; }
            if (binhi < 0 && cum + h > (unsigned)khi) { binhi = bkt; below_hi = (int)cum; }
            cum += h;
            if (binhi >= 0) break;
        }
        s_binlo = binlo; s_binhi = binhi; s_below_lo = below_lo; s_below_hi = below_hi;
    }
    __syncthreads();
    if (tid < 128) { f1[tid] = 0; f2[tid] = 0; }
    __syncthreads();
    int binlo = s_binlo, binhi = s_binhi;
    for (unsigned i = tid; i < ns; i += 256) {
        int v = (int)vals[i];
        int bkt = v >> 7;
        if (bkt == binlo) atomicAdd(&f1[v & 127], 1u);
        if (bkt == binhi && binhi != binlo) atomicAdd(&f2[v & 127], 1u);
    }
    __syncthreads();
    if (tid == 0) {
        int rlo = klo - s_below_lo;
        unsigned cum = 0; int d2lo = binlo << 7, d2hi = binhi << 7;
        for (int j = 0; j < 128; ++j) {
            cum += f1[j];
            if ((int)cum > rlo) { d2lo = (binlo << 7) + j; break; }
        }
        if (binhi == binlo) {
            int rhi = khi - s_below_lo;
            cum = 0;
            for (int j = 0; j < 128; ++j) {
                cum += f1[j];
                if ((int)cum > rhi) { d2hi = (binlo << 7) + j; break; }
            }
        } else {
            int rhi = khi - s_below_hi;
            cum = 0;
            for (int j = 0; j < 128; ++j) {
                cum += f2[j];
                if ((int)cum > rhi) { d2hi = (binhi << 7) + j; break; }
            }
        }
        float vlo = sqrtf((float)d2lo);
        float vhi = sqrtf((float)d2hi);
        float frac = idxf - floorf(idxf);
        res[pair * 2 + dir] = vlo + (vhi - vlo) * frac;
    }
}

// 1 block, 128 threads: parallel-load res+presence into LDS, lane 0 combines.
__global__ void k_final(const unsigned int* __restrict__ cnt, const float* __restrict__ res,
                        float* __restrict__ out) {
    __shared__ float s_res[104];
    __shared__ unsigned s_pres[52];
    int tid = threadIdx.x;
    if (tid < 104) s_res[tid] = res[tid];
    if (tid < 52) s_pres[tid] = cnt[260 + tid];
    __syncthreads();
    if (tid != 0) return;
    float total = 0.f, nvalid = 0.f;
    bool anyv = false;
    for (int b = 0; b < NB; ++b) {
        float num = 0.f, den = 0.f;
        for (int c = 0; c < NC; ++c) {
            int pair = b * NC + c;
            bool present = s_pres[pair] > 0;
            float dpt = s_res[pair * 2];
            float dtp = s_res[pair * 2 + 1];
            float hd;
            if (isnan(dpt) || isnan(dtp)) hd = nanf("");
            else hd = fmaxf(dpt, dtp);
            if (present) { num += hd; den += 1.f; }
        }
        float bm = num / fmaxf(den, 1.f);
        if (den > 0.f) { total += bm; nvalid += 1.f; anyv = true; }
    }
    out[0] = anyv ? (total / fmaxf(nvalid, 1.f)) : INFINITY;
}

extern "C" void kernel_launch(void* const* d_in, const int* in_sizes, int n_in,
                              void* d_out, int out_size, void* d_ws, size_t ws_size,
                              hipStream_t stream) {
    const float* pred = (const float*)d_in[0];
    const float* targ = (const float*)d_in[1];
    float* out = (float*)d_out;
    char* ws = (char*)d_ws;

    unsigned char* pl = (unsigned char*)(ws + PL_OFF);
    unsigned char* tl = (unsigned char*)(ws + TL_OFF);
    unsigned int* cnt = (unsigned int*)(ws + CNT_OFF);
    float* res = (float*)(ws + RES_OFF);
    unsigned int* bmp = (unsigned int*)(ws + BMP_OFF);
    unsigned short* listP = (unsigned short*)(ws + LISTP_OFF);
    unsigned short* listT = (unsigned short*)(ws + LISTT_OFF);
    float* minP = (float*)(ws + MINP_OFF);
    float* minT = (float*)(ws + MINT_OFF);

    k_labels<<<256, 128, 0, stream>>>((const float4*)pred, (const float4*)targ,
                                      (uchar4*)pl, (uchar4*)tl, cnt);
    k_rowbm<<<512, 256, 0, stream>>>(pl, tl, bmp, cnt, listP, listT);
    k_ring<<<dim3(12, 52, 2), 256, 0, stream>>>(cnt, bmp, listP, listT, minP, minT);
    k_select<<<dim3(52, 2), 256, 0, stream>>>(cnt, minP, minT, res);
    k_final<<<1, 128, 0, stream>>>(cnt, res, out);
}